// Round 11
// baseline (2319.070 us; speedup 1.0000x reference)
//
#include <hip/hip_runtime.h>
#include <math.h>

// Problem constants
#define BB   8
#define LL   512
#define DD   768
#define G4   3072      // 4*D
#define NW   3
#define NLAB 9
#define MM   4096      // B*L

typedef unsigned short u16;
typedef __attribute__((ext_vector_type(8))) __bf16 bf16x8;
typedef __attribute__((ext_vector_type(4))) float  f32x4;

#define AS1 __attribute__((address_space(1)))
#define AS3 __attribute__((address_space(3)))

// ---------------- workspace layout (bytes) ----------------
#define OFF_G    ((size_t)0)
#define OFF_C    ((size_t)75497472)
#define OFF_H    ((size_t)113246208)
#define OFF_XB   ((size_t)150994944)
#define OFF_WIHB ((size_t)157286400)
#define OFF_WHHB ((size_t)171442176)

// ---- fast hardware transcendentals (v_exp_f32 = 2^x, v_rcp_f32) ----
#if __has_builtin(__builtin_amdgcn_exp2f)
#define FEXP2(x) __builtin_amdgcn_exp2f(x)
#else
#define FEXP2(x) exp2f(x)
#endif
#if __has_builtin(__builtin_amdgcn_rcpf)
#define FRCP(x) __builtin_amdgcn_rcpf(x)
#else
#define FRCP(x) (1.0f / (x))
#endif
#define LOG2E  1.4426950408889634f
#define LOG2E2 2.8853900817779268f

__device__ __forceinline__ float sigm(float x) {
    return FRCP(1.0f + FEXP2(-LOG2E * x));
}
__device__ __forceinline__ float ftanh(float x) {
    return 1.0f - 2.0f * FRCP(1.0f + FEXP2(LOG2E2 * x));
}

__device__ __forceinline__ u16 f2bf(float f) {
    union { float f; unsigned u; } v; v.f = f;
    unsigned r = v.u + 0x7FFFu + ((v.u >> 16) & 1u);   // RNE
    return (u16)(r >> 16);
}
__device__ __forceinline__ float bf2f(u16 h) {
    union { unsigned u; float f; } v; v.u = ((unsigned)h) << 16;
    return v.f;
}

// ---------------------------------------------------------------------------
// Fused fp32 -> bf16 convert for x, W_ih, W_hh (one launch)
// ---------------------------------------------------------------------------
__global__ __launch_bounds__(256)
void k_cvt3(const float* __restrict__ a, const float* __restrict__ b,
            const float* __restrict__ c,
            u16* __restrict__ oa, u16* __restrict__ ob, u16* __restrict__ oc,
            int na4, int nb4, int nc4)
{
    int i = blockIdx.x * 256 + threadIdx.x;
    const float* src; u16* dst; int j;
    if (i < na4)                  { src = a; dst = oa; j = i; }
    else if (i < na4 + nb4)       { src = b; dst = ob; j = i - na4; }
    else if (i < na4 + nb4 + nc4) { src = c; dst = oc; j = i - na4 - nb4; }
    else return;
    float4 v = reinterpret_cast<const float4*>(src)[j];
    ushort4 o;
    o.x = f2bf(v.x); o.y = f2bf(v.y); o.z = f2bf(v.z); o.w = f2bf(v.w);
    reinterpret_cast<ushort4*>(dst)[j] = o;
}

// ---------------------------------------------------------------------------
// bf16 MFMA GEMM, 256x256 tile, BK=64, 512 threads = 8 waves (2M x 4N),
// SINGLE-buffered LDS (64 KB) -> 2 blocks/CU (16 waves).
//
// Round-9 findings: (a) rect XCD swizzle validated (FETCH 164->113.7 MB,
// keep); (b) counted-vmcnt depth-2 pipeline on a 1-block/CU 128KB-LDS
// structure is latency-bound (163us vs throughput floors ~30us, MfmaUtil
// 14%) -- intra-block pipelining can't replace cross-block overlap.
// Round-6 showed 2-3 blocks/CU with the simple stage->sync->compute->sync
// loop hides staging/epilogue latency via inter-block phase diversity
// (m114). This kernel = 256^2 staged-bytes win (884->442 MB/dispatch)
// + round-6's proven sync structure + rect swizzle.
//
// global_load_lds(16B), LDS linear dest + inverse-swizzled source, XOR slot
// swizzle on ds_read_b128 (slot ^= row&7) -> 2-way free (0 conflicts r3-r9).
//
// Gate-remapped B rows: p -> gate=(p>>4)&3, cell=(p&15)+16*(p>>6); each
// thread's 4 N-frags are the 4 gates (i,f,g,o) of one cell.
//
// MODE 0: Gp = bf16(x @ W_ih^T + b) packed ushort4 + fused t=0 cell init.
// MODE 1: gates = h_prev @ W_hh^T ; fused LSTM cell epilogue.
// ---------------------------------------------------------------------------
template<int MODE>
__global__ __launch_bounds__(512, 4)
void k_mfma(const u16* __restrict__ Ab,      // MODE0: xb ; MODE1: H prev base
            const u16* __restrict__ Wb,      // bf16 weights [NW][G4][DD]
            const float* __restrict__ bih,
            const float* __restrict__ bhh,
            u16* __restrict__ Gp,            // packed gates [NW][MM][DD][4]
            u16* __restrict__ hnext,
            float* __restrict__ cbuf,
            int kmin, int s)
{
    const int k = kmin + blockIdx.z;

    // XCD rectangle swizzle (validated r9: FETCH -31%): xcd = f%8, each XCD
    // covers bx in [(c&3)*4, +4), by in [(c>>2)*6, +6). Bijective; per-XCD
    // working set A 1.6MB + W 2.4MB ~= one 4MB L2.
    const int f  = blockIdx.y * 16 + blockIdx.x;
    const int c  = f & 7;
    const int j_ = f >> 3;                   // 0..23
    const int bx = (c & 3) * 4 + (j_ & 3);
    const int by = (c >> 2) * 6 + (j_ >> 2);
    const int r0 = bx * 256;                 // M origin
    const int n0 = by * 64;                  // cell origin (64 cells per tile)

    const int tid  = threadIdx.x;
    const int lane = tid & 63;
    const int wid  = tid >> 6;               // 0..7
    const int wm   = wid >> 2;               // 0..1  (M half)
    const int wn   = wid & 3;                // 0..3  (N quarter)

    __shared__ bf16x8 As[2048];              // [256 rows][8 slots] = 32 KB
    __shared__ bf16x8 Bs[2048];              // 32 KB

    const u16* Asrc = (MODE == 0) ? Ab : (Ab + (size_t)k * MM * DD);
    const u16* Wk   = Wb + (size_t)k * G4 * DD;

    // ---- staging addresses (linear LDS dest, inverse-swizzled source) ----
    const int sg = (tid & 7) ^ ((tid >> 3) & 7);   // k-slot involution
    const u16* gA[4]; const u16* gB[4];
#pragma unroll
    for (int i = 0; i < 4; ++i) {
        int rowA = i * 64 + (tid >> 3);            // 0..255
        gA[i] = Asrc + (size_t)(r0 + rowA) * DD + sg * 8;
        int p    = rowA;                           // B LDS row
        int g    = (p >> 4) & 3;
        int cell = (p & 15) + 16 * (p >> 6);
        int j    = g * DD + n0 + cell;
        gB[i] = Wk + (size_t)j * DD + sg * 8;
    }

    auto stage = [&](int k0) {                     // 8 loads per thread
#pragma unroll
        for (int i = 0; i < 4; ++i) {
            __builtin_amdgcn_global_load_lds(
                (const AS1 void*)(gA[i] + k0),
                (AS3 void*)&As[i * 512 + tid], 16, 0, 0);
            __builtin_amdgcn_global_load_lds(
                (const AS1 void*)(gB[i] + k0),
                (AS3 void*)&Bs[i * 512 + tid], 16, 0, 0);
        }
    };

    f32x4 acc[8][4];
#pragma unroll
    for (int a = 0; a < 8; ++a)
#pragma unroll
        for (int b = 0; b < 4; ++b) acc[a][b] = (f32x4)0.0f;

    const int c15 = lane & 15;
    const int khi = lane >> 4;               // 0..3

    for (int t = 0; t < 12; ++t) {           // K = 12 * 64
        stage(t * 64);
        __syncthreads();                     // loads landed (vmcnt0+barrier)
#pragma unroll
        for (int ks = 0; ks < 2; ++ks) {
            bf16x8 af[8], bfr[4];
#pragma unroll
            for (int mi = 0; mi < 8; ++mi) {
                int row  = wm * 128 + mi * 16 + c15;
                int slot = (ks * 4 + khi) ^ (row & 7);
                af[mi] = As[row * 8 + slot];
            }
#pragma unroll
            for (int ni = 0; ni < 4; ++ni) {
                int row  = wn * 64 + ni * 16 + c15;
                int slot = (ks * 4 + khi) ^ (row & 7);
                bfr[ni] = Bs[row * 8 + slot];
            }
#pragma unroll
            for (int mi = 0; mi < 8; ++mi)
#pragma unroll
                for (int ni = 0; ni < 4; ++ni)
                    acc[mi][ni] = __builtin_amdgcn_mfma_f32_16x16x32_bf16(
                        af[mi], bfr[ni], acc[mi][ni], 0, 0, 0);
        }
        __syncthreads();                     // reads done before next stage
    }

    // ---- epilogue ----
    const int n  = n0 + 16 * wn + c15;       // this thread's cell index
    const int hw = k + 1;                    // half window 1,2,3

    if (MODE == 0) {
        u16*   Gk = Gp    + ((size_t)k * MM * DD) * 4;
        u16*   h0 = hnext + (size_t)k * MM * DD;
        float* c0 = cbuf  + (size_t)k * MM * DD;
        const float bs0 = bih[k * G4 + 0 * DD + n] + bhh[k * G4 + 0 * DD + n];
        const float bs1 = bih[k * G4 + 1 * DD + n] + bhh[k * G4 + 1 * DD + n];
        const float bs2 = bih[k * G4 + 2 * DD + n] + bhh[k * G4 + 2 * DD + n];
        const float bs3 = bih[k * G4 + 3 * DD + n] + bhh[k * G4 + 3 * DD + n];
#pragma unroll
        for (int mi = 0; mi < 8; ++mi)
#pragma unroll
            for (int q = 0; q < 4; ++q) {
                int r = r0 + wm * 128 + mi * 16 + khi * 4 + q;
                float p0 = acc[mi][0][q] + bs0;
                float p1 = acc[mi][1][q] + bs1;
                float p2 = acc[mi][2][q] + bs2;
                float p3 = acc[mi][3][q] + bs3;
                ushort4 pk;
                pk.x = f2bf(p0); pk.y = f2bf(p1); pk.z = f2bf(p2); pk.w = f2bf(p3);
                *reinterpret_cast<ushort4*>(Gk + ((size_t)r * DD + n) * 4) = pk;
                // fused t=0 init at shifted row (l+hw) mod LL
                int l  = r & (LL - 1);
                bool ok = (l + hw) < LL;
                int rt = ok ? (r + hw) : (r + hw - LL);
                float iv = sigm(p0), gv = ftanh(p2), ov = sigm(p3);
                float cn = iv * gv;
                float hv = ov * ftanh(cn);
                size_t offt = (size_t)rt * DD + n;
                c0[offt] = ok ? cn : 0.0f;
                h0[offt] = ok ? f2bf(hv) : (u16)0;
            }
    } else {
        const u16* Gk = Gp + ((size_t)k * MM * DD) * 4;
        u16*  hn = hnext + (size_t)k * MM * DD;
        const u16* hp = Asrc;
        float* ck = cbuf + (size_t)k * MM * DD;
#pragma unroll
        for (int mi = 0; mi < 8; ++mi)
#pragma unroll
            for (int q = 0; q < 4; ++q) {
                int r = r0 + wm * 128 + mi * 16 + khi * 4 + q;
                int l = r & (LL - 1);
                int pos = l - hw + s;
                bool valid = (pos >= 0) && (pos < LL);
                int posc = min(max(pos, 0), LL - 1);
                ushort4 g4 = *reinterpret_cast<const ushort4*>(
                    Gk + ((size_t)(r - l + posc) * DD + n) * 4);
                float gi = sigm (acc[mi][0][q] + bf2f(g4.x));
                float gf = sigm (acc[mi][1][q] + bf2f(g4.y));
                float gg = ftanh(acc[mi][2][q] + bf2f(g4.z));
                float go = sigm (acc[mi][3][q] + bf2f(g4.w));
                size_t off = (size_t)r * DD + n;
                if (valid) {
                    float cold = ck[off];
                    float cnew = gf * cold + gi * gg;
                    ck[off] = cnew;
                    hn[off] = f2bf(go * ftanh(cnew));
                } else {
                    hn[off] = hp[off];           // carry h through
                }
            }
    }
}

// ---------------------------------------------------------------------------
// Epilogue: attn over 3 windows, softmax, residual, 9-label linear.
// One wave per row; butterfly shuffle reductions. All fp32 math.
// ---------------------------------------------------------------------------
__global__ __launch_bounds__(256)
void k_final(const float* __restrict__ x, const u16* __restrict__ hfin,
             const float* __restrict__ linw, const float* __restrict__ linb,
             float* __restrict__ out)
{
    int wave = threadIdx.x >> 6, lane = threadIdx.x & 63;
    int r = blockIdx.x * 4 + wave;
    const float* xr = x + (size_t)r * DD;
    const u16* h0 = hfin + (size_t)0 * MM * DD + (size_t)r * DD;
    const u16* h1 = hfin + (size_t)1 * MM * DD + (size_t)r * DD;
    const u16* h2 = hfin + (size_t)2 * MM * DD + (size_t)r * DD;

    float xe[12], he0[12], he1[12], he2[12];
    float s0 = 0.f, s1 = 0.f, s2 = 0.f;
#pragma unroll
    for (int q = 0; q < 12; ++q) {
        int e = lane + 64 * q;
        xe[q] = xr[e];
        he0[q] = bf2f(h0[e]); he1[q] = bf2f(h1[e]); he2[q] = bf2f(h2[e]);
        s0 = fmaf(xe[q], he0[q], s0);
        s1 = fmaf(xe[q], he1[q], s1);
        s2 = fmaf(xe[q], he2[q], s2);
    }
#pragma unroll
    for (int d = 1; d < 64; d <<= 1) {
        s0 += __shfl_xor(s0, d, 64);
        s1 += __shfl_xor(s1, d, 64);
        s2 += __shfl_xor(s2, d, 64);
    }
    const float scale = 0.03608439182435161f;      // 1/sqrt(768)
    s0 *= scale; s1 *= scale; s2 *= scale;
    float mx = fmaxf(s0, fmaxf(s1, s2));
    float e0 = FEXP2(LOG2E * (s0 - mx));
    float e1 = FEXP2(LOG2E * (s1 - mx));
    float e2 = FEXP2(LOG2E * (s2 - mx));
    float inv = FRCP(e0 + e1 + e2);
    float a0 = e0 * inv, a1 = e1 * inv, a2 = e2 * inv;

    float p[9];
#pragma unroll
    for (int j = 0; j < 9; ++j) p[j] = 0.0f;
#pragma unroll
    for (int q = 0; q < 12; ++q) {
        int e = lane + 64 * q;
        float o = xe[q] + a0 * he0[q] + a1 * he1[q] + a2 * he2[q];
#pragma unroll
        for (int j = 0; j < 9; ++j)
            p[j] = fmaf(o, linw[j * DD + e], p[j]);
    }
#pragma unroll
    for (int j = 0; j < 9; ++j)
#pragma unroll
        for (int d = 1; d < 64; d <<= 1)
            p[j] += __shfl_xor(p[j], d, 64);
    if (lane == 0) {
#pragma unroll
        for (int j = 0; j < 9; ++j)
            out[(size_t)r * NLAB + j] = p[j] + linb[j];
    }
}

// ---------------------------------------------------------------------------
extern "C" void kernel_launch(void* const* d_in, const int* in_sizes, int n_in,
                              void* d_out, int out_size, void* d_ws, size_t ws_size,
                              hipStream_t stream)
{
    const float* x    = (const float*)d_in[0];
    const float* Wih  = (const float*)d_in[1];
    const float* Whh  = (const float*)d_in[2];
    const float* bih  = (const float*)d_in[3];
    const float* bhh  = (const float*)d_in[4];
    const float* linw = (const float*)d_in[5];
    const float* linb = (const float*)d_in[6];
    float* out = (float*)d_out;
    char*  ws  = (char*)d_ws;

    u16*   Gp   = (u16*)  (ws + OFF_G);
    float* C    = (float*)(ws + OFF_C);
    u16*   H    = (u16*)  (ws + OFF_H);     // 2 ping-pong bufs of NW*MM*DD
    u16*   xb   = (u16*)  (ws + OFF_XB);
    u16*   Wihb = (u16*)  (ws + OFF_WIHB);
    u16*   Whhb = (u16*)  (ws + OFF_WHHB);

    dim3 blk(256);
    dim3 blkG(512);

    // 0) operand conversion to bf16 (single fused launch)
    const int na4 = MM * DD / 4;
    const int nb4 = NW * G4 * DD / 4;
    k_cvt3<<<(na4 + 2 * nb4 + 255) / 256, blk, 0, stream>>>(
        x, Wih, Whh, xb, Wihb, Whhb, na4, nb4, nb4);

    // 1) input gates (packed bf16) + fused t=0 cell init -> H buf0, C
    k_mfma<0><<<dim3(16, 12, 3), blkG, 0, stream>>>(
        xb, Wihb, bih, bhh, Gp, H, C, 0, 0);

    // 2) steps s=1..6; windows {3,5,7} aligned at start, batched via grid.z
    for (int s = 1; s < 7; ++s) {
        int kmin = (s < 3) ? 0 : ((s < 5) ? 1 : 2);
        int nact = 3 - kmin;
        u16* hprev = H + (size_t)((s - 1) & 1) * NW * MM * DD;
        u16* hnx   = H + (size_t)(s & 1) * NW * MM * DD;
        k_mfma<1><<<dim3(16, 12, nact), blkG, 0, stream>>>(
            hprev, Whhb, nullptr, nullptr, Gp, hnx, C, kmin, s);
    }
    // odd window widths -> final h lands in buffer 0

    // 3) attention over windows + residual + classifier
    k_final<<<MM / 4, blk, 0, stream>>>(x, H, linw, linb, out);
}

// Round 12
// 648.337 us; speedup vs baseline: 3.5770x; 3.5770x over previous
//
#include <hip/hip_runtime.h>
#include <math.h>

// Problem constants
#define BB   8
#define LL   512
#define DD   768
#define G4   3072      // 4*D
#define NW   3
#define NLAB 9
#define MM   4096      // B*L

typedef unsigned short u16;
typedef __attribute__((ext_vector_type(8))) __bf16 bf16x8;
typedef __attribute__((ext_vector_type(4))) float  f32x4;

#define AS1 __attribute__((address_space(1)))
#define AS3 __attribute__((address_space(3)))

// ---------------- workspace layout (bytes) ----------------
#define OFF_G    ((size_t)0)
#define OFF_C    ((size_t)75497472)
#define OFF_H    ((size_t)113246208)
#define OFF_XB   ((size_t)150994944)
#define OFF_WIHB ((size_t)157286400)
#define OFF_WHHB ((size_t)171442176)

// ---- fast hardware transcendentals (v_exp_f32 = 2^x, v_rcp_f32) ----
#if __has_builtin(__builtin_amdgcn_exp2f)
#define FEXP2(x) __builtin_amdgcn_exp2f(x)
#else
#define FEXP2(x) exp2f(x)
#endif
#if __has_builtin(__builtin_amdgcn_rcpf)
#define FRCP(x) __builtin_amdgcn_rcpf(x)
#else
#define FRCP(x) (1.0f / (x))
#endif
#define LOG2E  1.4426950408889634f
#define LOG2E2 2.8853900817779268f

__device__ __forceinline__ float sigm(float x) {
    return FRCP(1.0f + FEXP2(-LOG2E * x));
}
__device__ __forceinline__ float ftanh(float x) {
    return 1.0f - 2.0f * FRCP(1.0f + FEXP2(LOG2E2 * x));
}

__device__ __forceinline__ u16 f2bf(float f) {
    union { float f; unsigned u; } v; v.f = f;
    unsigned r = v.u + 0x7FFFu + ((v.u >> 16) & 1u);   // RNE
    return (u16)(r >> 16);
}
__device__ __forceinline__ float bf2f(u16 h) {
    union { unsigned u; float f; } v; v.u = ((unsigned)h) << 16;
    return v.f;
}

// ---------------------------------------------------------------------------
// Fused fp32 -> bf16 convert for x, W_ih, W_hh (one launch)
// ---------------------------------------------------------------------------
__global__ __launch_bounds__(256)
void k_cvt3(const float* __restrict__ a, const float* __restrict__ b,
            const float* __restrict__ c,
            u16* __restrict__ oa, u16* __restrict__ ob, u16* __restrict__ oc,
            int na4, int nb4, int nc4)
{
    int i = blockIdx.x * 256 + threadIdx.x;
    const float* src; u16* dst; int j;
    if (i < na4)                  { src = a; dst = oa; j = i; }
    else if (i < na4 + nb4)       { src = b; dst = ob; j = i - na4; }
    else if (i < na4 + nb4 + nc4) { src = c; dst = oc; j = i - na4 - nb4; }
    else return;
    float4 v = reinterpret_cast<const float4*>(src)[j];
    ushort4 o;
    o.x = f2bf(v.x); o.y = f2bf(v.y); o.z = f2bf(v.z); o.w = f2bf(v.w);
    reinterpret_cast<ushort4*>(dst)[j] = o;
}

// ---------------------------------------------------------------------------
// bf16 MFMA GEMM, 256x256 tile, BK=64, 1024 threads = 16 waves (4M x 4N),
// each wave owns a 64x64 sub-tile (4x4 frags of 16x16x32 -> acc[4][4]).
// SINGLE-buffered LDS (64 KB), proven stage->sync->MFMA->sync loop.
//
// Round-11 finding (spill erratum): 8-wave 256^2 needs ~190 unified
// VGPR/AGPR; any cap at 128 (which 2-blocks/CU or a 1024-thread block
// requires) spills acc to scratch -> 1.5 GB/dispatch spill traffic.
// The 16-wave decomposition brings per-thread state to ~110 regs
// (acc 64 + frags 32 + addr) -- the SAME per-wave shape as the r5/r6
// kernel that measured 96 VGPR. 16 waves/CU doubles outstanding
// global_load_lds vs r7/r9's 8 -> staging fill-rate up (r6 evidence:
// fill scales with resident waves), while 256^2 keeps staged bytes at
// 442 MB/z3-dispatch (half of 128^2's 884).
//
// Rect XCD swizzle validated r9 (FETCH 164->113.7 MB): per-XCD 4bx x 6by
// rectangle, working set ~4MB = one XCD L2.
//
// global_load_lds(16B), LDS linear dest + inverse-swizzled source, XOR slot
// swizzle on ds_read_b128 (slot ^= row&7) -> 2-way free (0 conflicts r3-r11).
//
// Gate-remapped B rows: p in [0,256) -> gate=(p>>4)&3, cell=(p&15)+16*(p>>6);
// wave wn's 4 N-frags = the 4 gates (i,f,g,o) of cells 16*wn..16*wn+15.
//
// MODE 0: Gp = bf16(x @ W_ih^T + b) packed ushort4 + fused t=0 cell init.
// MODE 1: gates = h_prev @ W_hh^T ; fused LSTM cell epilogue.
// ---------------------------------------------------------------------------
template<int MODE>
__global__ __launch_bounds__(1024)
void k_mfma(const u16* __restrict__ Ab,      // MODE0: xb ; MODE1: H prev base
            const u16* __restrict__ Wb,      // bf16 weights [NW][G4][DD]
            const float* __restrict__ bih,
            const float* __restrict__ bhh,
            u16* __restrict__ Gp,            // packed gates [NW][MM][DD][4]
            u16* __restrict__ hnext,
            float* __restrict__ cbuf,
            int kmin, int s)
{
    const int k = kmin + blockIdx.z;

    // XCD rectangle swizzle (validated r9): xcd = f%8, each XCD covers
    // bx in [(c&3)*4, +4), by in [(c>>2)*6, +6). Bijective over 16x12.
    const int f  = blockIdx.y * 16 + blockIdx.x;
    const int c  = f & 7;
    const int j_ = f >> 3;                   // 0..23
    const int bx = (c & 3) * 4 + (j_ & 3);
    const int by = (c >> 2) * 6 + (j_ >> 2);
    const int r0 = bx * 256;                 // M origin
    const int n0 = by * 64;                  // cell origin (64 cells per tile)

    const int tid  = threadIdx.x;
    const int lane = tid & 63;
    const int wid  = tid >> 6;               // 0..15
    const int wm   = wid >> 2;               // 0..3  (M quarter)
    const int wn   = wid & 3;                // 0..3  (N quarter / cell group)

    __shared__ bf16x8 As[2048];              // [256 rows][8 slots] = 32 KB
    __shared__ bf16x8 Bs[2048];              // 32 KB

    const u16* Asrc = (MODE == 0) ? Ab : (Ab + (size_t)k * MM * DD);
    const u16* Wk   = Wb + (size_t)k * G4 * DD;

    // ---- staging addresses (linear LDS dest, inverse-swizzled source) ----
    // 1024 threads x (2 A + 2 B) 16B loads per K-step = 64 KB.
    const int sg = (tid & 7) ^ ((tid >> 3) & 7);   // k-slot involution
    const int p0 = tid >> 3;                       // rows 0..127
    auto bRow = [&](int p) {                       // W row for B LDS row p
        int g    = (p >> 4) & 3;
        int cell = (p & 15) + 16 * (p >> 6);
        return g * DD + n0 + cell;
    };
    const u16* gA0 = Asrc + (size_t)(r0 + p0) * DD + sg * 8;
    const u16* gA1 = gA0 + (size_t)128 * DD;
    const u16* gB0 = Wk + (size_t)bRow(p0) * DD + sg * 8;
    const u16* gB1 = Wk + (size_t)bRow(p0 + 128) * DD + sg * 8;

    auto stage = [&](int k0) {                     // 4 loads per thread
        __builtin_amdgcn_global_load_lds((const AS1 void*)(gA0 + k0),
            (AS3 void*)&As[tid], 16, 0, 0);
        __builtin_amdgcn_global_load_lds((const AS1 void*)(gA1 + k0),
            (AS3 void*)&As[1024 + tid], 16, 0, 0);
        __builtin_amdgcn_global_load_lds((const AS1 void*)(gB0 + k0),
            (AS3 void*)&Bs[tid], 16, 0, 0);
        __builtin_amdgcn_global_load_lds((const AS1 void*)(gB1 + k0),
            (AS3 void*)&Bs[1024 + tid], 16, 0, 0);
    };

    f32x4 acc[4][4];
#pragma unroll
    for (int a = 0; a < 4; ++a)
#pragma unroll
        for (int b = 0; b < 4; ++b) acc[a][b] = (f32x4)0.0f;

    const int c15 = lane & 15;
    const int khi = lane >> 4;               // 0..3

    for (int t = 0; t < 12; ++t) {           // K = 12 * 64
        stage(t * 64);
        __syncthreads();                     // loads landed (vmcnt0+barrier)
#pragma unroll
        for (int ks = 0; ks < 2; ++ks) {
            bf16x8 af[4], bfr[4];
#pragma unroll
            for (int mi = 0; mi < 4; ++mi) {
                int row  = wm * 64 + mi * 16 + c15;
                int slot = (ks * 4 + khi) ^ (row & 7);
                af[mi] = As[row * 8 + slot];
            }
#pragma unroll
            for (int ni = 0; ni < 4; ++ni) {
                int row  = wn * 64 + ni * 16 + c15;
                int slot = (ks * 4 + khi) ^ (row & 7);
                bfr[ni] = Bs[row * 8 + slot];
            }
#pragma unroll
            for (int mi = 0; mi < 4; ++mi)
#pragma unroll
                for (int ni = 0; ni < 4; ++ni)
                    acc[mi][ni] = __builtin_amdgcn_mfma_f32_16x16x32_bf16(
                        af[mi], bfr[ni], acc[mi][ni], 0, 0, 0);
        }
        __syncthreads();                     // reads done before next stage
    }

    // ---- epilogue ----
    const int n  = n0 + 16 * wn + c15;       // this thread's cell index
    const int hw = k + 1;                    // half window 1,2,3

    if (MODE == 0) {
        u16*   Gk = Gp    + ((size_t)k * MM * DD) * 4;
        u16*   h0 = hnext + (size_t)k * MM * DD;
        float* c0 = cbuf  + (size_t)k * MM * DD;
        const float bs0 = bih[k * G4 + 0 * DD + n] + bhh[k * G4 + 0 * DD + n];
        const float bs1 = bih[k * G4 + 1 * DD + n] + bhh[k * G4 + 1 * DD + n];
        const float bs2 = bih[k * G4 + 2 * DD + n] + bhh[k * G4 + 2 * DD + n];
        const float bs3 = bih[k * G4 + 3 * DD + n] + bhh[k * G4 + 3 * DD + n];
#pragma unroll
        for (int mi = 0; mi < 4; ++mi)
#pragma unroll
            for (int q = 0; q < 4; ++q) {
                int r = r0 + wm * 64 + mi * 16 + khi * 4 + q;
                float p0_ = acc[mi][0][q] + bs0;
                float p1_ = acc[mi][1][q] + bs1;
                float p2_ = acc[mi][2][q] + bs2;
                float p3_ = acc[mi][3][q] + bs3;
                ushort4 pk;
                pk.x = f2bf(p0_); pk.y = f2bf(p1_);
                pk.z = f2bf(p2_); pk.w = f2bf(p3_);
                *reinterpret_cast<ushort4*>(Gk + ((size_t)r * DD + n) * 4) = pk;
                // fused t=0 init at shifted row (l+hw) mod LL
                int l  = r & (LL - 1);
                bool ok = (l + hw) < LL;
                int rt = ok ? (r + hw) : (r + hw - LL);
                float iv = sigm(p0_), gv = ftanh(p2_), ov = sigm(p3_);
                float cn = iv * gv;
                float hv = ov * ftanh(cn);
                size_t offt = (size_t)rt * DD + n;
                c0[offt] = ok ? cn : 0.0f;
                h0[offt] = ok ? f2bf(hv) : (u16)0;
            }
    } else {
        const u16* Gk = Gp + ((size_t)k * MM * DD) * 4;
        u16*  hn = hnext + (size_t)k * MM * DD;
        const u16* hp = Asrc;
        float* ck = cbuf + (size_t)k * MM * DD;
#pragma unroll
        for (int mi = 0; mi < 4; ++mi)
#pragma unroll
            for (int q = 0; q < 4; ++q) {
                int r = r0 + wm * 64 + mi * 16 + khi * 4 + q;
                int l = r & (LL - 1);
                int pos = l - hw + s;
                bool valid = (pos >= 0) && (pos < LL);
                int posc = min(max(pos, 0), LL - 1);
                ushort4 g4 = *reinterpret_cast<const ushort4*>(
                    Gk + ((size_t)(r - l + posc) * DD + n) * 4);
                float gi = sigm (acc[mi][0][q] + bf2f(g4.x));
                float gf = sigm (acc[mi][1][q] + bf2f(g4.y));
                float gg = ftanh(acc[mi][2][q] + bf2f(g4.z));
                float go = sigm (acc[mi][3][q] + bf2f(g4.w));
                size_t off = (size_t)r * DD + n;
                if (valid) {
                    float cold = ck[off];
                    float cnew = gf * cold + gi * gg;
                    ck[off] = cnew;
                    hn[off] = f2bf(go * ftanh(cnew));
                } else {
                    hn[off] = hp[off];           // carry h through
                }
            }
    }
}

// ---------------------------------------------------------------------------
// Epilogue: attn over 3 windows, softmax, residual, 9-label linear.
// One wave per row; butterfly shuffle reductions. All fp32 math.
// ---------------------------------------------------------------------------
__global__ __launch_bounds__(256)
void k_final(const float* __restrict__ x, const u16* __restrict__ hfin,
             const float* __restrict__ linw, const float* __restrict__ linb,
             float* __restrict__ out)
{
    int wave = threadIdx.x >> 6, lane = threadIdx.x & 63;
    int r = blockIdx.x * 4 + wave;
    const float* xr = x + (size_t)r * DD;
    const u16* h0 = hfin + (size_t)0 * MM * DD + (size_t)r * DD;
    const u16* h1 = hfin + (size_t)1 * MM * DD + (size_t)r * DD;
    const u16* h2 = hfin + (size_t)2 * MM * DD + (size_t)r * DD;

    float xe[12], he0[12], he1[12], he2[12];
    float s0 = 0.f, s1 = 0.f, s2 = 0.f;
#pragma unroll
    for (int q = 0; q < 12; ++q) {
        int e = lane + 64 * q;
        xe[q] = xr[e];
        he0[q] = bf2f(h0[e]); he1[q] = bf2f(h1[e]); he2[q] = bf2f(h2[e]);
        s0 = fmaf(xe[q], he0[q], s0);
        s1 = fmaf(xe[q], he1[q], s1);
        s2 = fmaf(xe[q], he2[q], s2);
    }
#pragma unroll
    for (int d = 1; d < 64; d <<= 1) {
        s0 += __shfl_xor(s0, d, 64);
        s1 += __shfl_xor(s1, d, 64);
        s2 += __shfl_xor(s2, d, 64);
    }
    const float scale = 0.03608439182435161f;      // 1/sqrt(768)
    s0 *= scale; s1 *= scale; s2 *= scale;
    float mx = fmaxf(s0, fmaxf(s1, s2));
    float e0 = FEXP2(LOG2E * (s0 - mx));
    float e1 = FEXP2(LOG2E * (s1 - mx));
    float e2 = FEXP2(LOG2E * (s2 - mx));
    float inv = FRCP(e0 + e1 + e2);
    float a0 = e0 * inv, a1 = e1 * inv, a2 = e2 * inv;

    float p[9];
#pragma unroll
    for (int j = 0; j < 9; ++j) p[j] = 0.0f;
#pragma unroll
    for (int q = 0; q < 12; ++q) {
        int e = lane + 64 * q;
        float o = xe[q] + a0 * he0[q] + a1 * he1[q] + a2 * he2[q];
#pragma unroll
        for (int j = 0; j < 9; ++j)
            p[j] = fmaf(o, linw[j * DD + e], p[j]);
    }
#pragma unroll
    for (int j = 0; j < 9; ++j)
#pragma unroll
        for (int d = 1; d < 64; d <<= 1)
            p[j] += __shfl_xor(p[j], d, 64);
    if (lane == 0) {
#pragma unroll
        for (int j = 0; j < 9; ++j)
            out[(size_t)r * NLAB + j] = p[j] + linb[j];
    }
}

// ---------------------------------------------------------------------------
extern "C" void kernel_launch(void* const* d_in, const int* in_sizes, int n_in,
                              void* d_out, int out_size, void* d_ws, size_t ws_size,
                              hipStream_t stream)
{
    const float* x    = (const float*)d_in[0];
    const float* Wih  = (const float*)d_in[1];
    const float* Whh  = (const float*)d_in[2];
    const float* bih  = (const float*)d_in[3];
    const float* bhh  = (const float*)d_in[4];
    const float* linw = (const float*)d_in[5];
    const float* linb = (const float*)d_in[6];
    float* out = (float*)d_out;
    char*  ws  = (char*)d_ws;

    u16*   Gp   = (u16*)  (ws + OFF_G);
    float* C    = (float*)(ws + OFF_C);
    u16*   H    = (u16*)  (ws + OFF_H);     // 2 ping-pong bufs of NW*MM*DD
    u16*   xb   = (u16*)  (ws + OFF_XB);
    u16*   Wihb = (u16*)  (ws + OFF_WIHB);
    u16*   Whhb = (u16*)  (ws + OFF_WHHB);

    dim3 blk(256);
    dim3 blkG(1024);

    // 0) operand conversion to bf16 (single fused launch)
    const int na4 = MM * DD / 4;
    const int nb4 = NW * G4 * DD / 4;
    k_cvt3<<<(na4 + 2 * nb4 + 255) / 256, blk, 0, stream>>>(
        x, Wih, Whh, xb, Wihb, Whhb, na4, nb4, nb4);

    // 1) input gates (packed bf16) + fused t=0 cell init -> H buf0, C
    k_mfma<0><<<dim3(16, 12, 3), blkG, 0, stream>>>(
        xb, Wihb, bih, bhh, Gp, H, C, 0, 0);

    // 2) steps s=1..6; windows {3,5,7} aligned at start, batched via grid.z
    for (int s = 1; s < 7; ++s) {
        int kmin = (s < 3) ? 0 : ((s < 5) ? 1 : 2);
        int nact = 3 - kmin;
        u16* hprev = H + (size_t)((s - 1) & 1) * NW * MM * DD;
        u16* hnx   = H + (size_t)(s & 1) * NW * MM * DD;
        k_mfma<1><<<dim3(16, 12, nact), blkG, 0, stream>>>(
            hprev, Whhb, nullptr, nullptr, Gp, hnx, C, kmin, s);
    }
    // odd window widths -> final h lands in buffer 0

    // 3) attention over windows + residual + classifier
    k_final<<<MM / 4, blk, 0, stream>>>(x, H, linw, linb, out);
}